// Round 6
// baseline (881.627 us; speedup 1.0000x reference)
//
#include <hip/hip_runtime.h>
#include <cstdint>
#include <cstddef>

#define T_DIM 256
#define H_DIM 4096
#define I_DIM 14336
// GROUP_SIZE = 64 -> gemm1: 64 groups (K=4096), gemm2: 224 groups (K=14336).

typedef __attribute__((ext_vector_type(8))) short s8v;   // 8 bf16 (MFMA A/B frag)
typedef __attribute__((ext_vector_type(4))) float f4v;   // MFMA C/D frag

// Workspace layout (bytes)
static constexpr size_t XS_OFF   = 0;                                   // x bf16 frag-major, 2 MiB
static constexpr size_t ACT_OFF  = (size_t)T_DIM * H_DIM * 2;           // act bf16 frag-major, 7.0 MiB
static constexpr size_t ACT_BYTES= (size_t)T_DIM * I_DIM * 2;
static constexpr size_t G1_OFF   = ACT_OFF + ACT_BYTES;                 // float2[64][I] (s, z*s)
static constexpr size_t G3_OFF   = G1_OFF + (size_t)64 * I_DIM * 8;
static constexpr size_t G2_OFF   = G3_OFF + (size_t)64 * I_DIM * 8;     // float2[224][H]
static constexpr size_t WS_NEED  = G2_OFF + (size_t)224 * H_DIM * 8;    // ~31.5 MB
static constexpr size_t WS_MIN   = G1_OFF;                              // ~9.4 MB (no-transpose path)

__device__ __forceinline__ unsigned short f2bf(float f) {
    unsigned u = __builtin_bit_cast(unsigned, f);
    u += 0x7fffu + ((u >> 16) & 1u);
    return (unsigned short)(u >> 16);
}

// dequant 8 ints -> 8 bf16 (RNE via v_cvt_pk_bf16_f32): w = q*s + ns, ns = -z*s
__device__ __forceinline__ s8v dq8f(const int4 qa, const int4 qb, float s, float ns) {
    float f0 = fmaf((float)qa.x, s, ns), f1 = fmaf((float)qa.y, s, ns);
    float f2 = fmaf((float)qa.z, s, ns), f3 = fmaf((float)qa.w, s, ns);
    float f4 = fmaf((float)qb.x, s, ns), f5 = fmaf((float)qb.y, s, ns);
    float f6 = fmaf((float)qb.z, s, ns), f7 = fmaf((float)qb.w, s, ns);
    unsigned r0, r1, r2, r3;
    asm("v_cvt_pk_bf16_f32 %0, %1, %2" : "=v"(r0) : "v"(f0), "v"(f1));
    asm("v_cvt_pk_bf16_f32 %0, %1, %2" : "=v"(r1) : "v"(f2), "v"(f3));
    asm("v_cvt_pk_bf16_f32 %0, %1, %2" : "=v"(r2) : "v"(f4), "v"(f5));
    asm("v_cvt_pk_bf16_f32 %0, %1, %2" : "=v"(r3) : "v"(f6), "v"(f7));
    union { unsigned u[4]; s8v v; } o;
    o.u[0] = r0; o.u[1] = r1; o.u[2] = r2; o.u[3] = r3;
    return o.v;
}

// ---------------------------------------------------------------------------
// k_prep: x fp32 [256,4096] -> bf16 A-fragment-major:
// frag f = ksub*16 + msub; lane l holds x[msub*16+(l&15)][ksub*32+(l>>4)*8 ..+7]
// at byte f*1024 + l*16.  (verified layout from R5)
// ---------------------------------------------------------------------------
__global__ __launch_bounds__(256) void k_prep(const float* __restrict__ x,
                                              unsigned short* __restrict__ xs) {
    int t = blockIdx.x * 256 + threadIdx.x;   // 0..131071
    int l = t & 63, f = t >> 6;
    int msub = f & 15, ksub = f >> 4;
    int m = msub * 16 + (l & 15);
    int k = ksub * 32 + (l >> 4) * 8;
    const float* xp = x + (size_t)m * H_DIM + k;
    float4 a = *(const float4*)xp;
    float4 b = *(const float4*)(xp + 4);
    union { unsigned short u[8]; s8v v; } r;
    r.u[0] = f2bf(a.x); r.u[1] = f2bf(a.y); r.u[2] = f2bf(a.z); r.u[3] = f2bf(a.w);
    r.u[4] = f2bf(b.x); r.u[5] = f2bf(b.y); r.u[6] = f2bf(b.z); r.u[7] = f2bf(b.w);
    *((s8v*)xs + t) = r.v;
}

// ---------------------------------------------------------------------------
// t_prep: transpose scales to [g][n] as float2(s, z*s) for coalesced loads.
// aid 0: w1 (64 x 14336), aid 1: w3, aid 2: w2 (224 x 4096). 3 x 917504 elems.
// ---------------------------------------------------------------------------
__global__ __launch_bounds__(256) void t_prep(
    const float* __restrict__ w1s, const float* __restrict__ w1z,
    const float* __restrict__ w3s, const float* __restrict__ w3z,
    const float* __restrict__ w2s, const float* __restrict__ w2z,
    float2* __restrict__ g1, float2* __restrict__ g3, float2* __restrict__ g2)
{
    int aid = blockIdx.x / 3584;
    int r   = (blockIdx.x - aid * 3584) * 256 + threadIdx.x;   // 0..917503
    if (aid < 2) {
        int n = r % I_DIM, g = r / I_DIM;
        const float* S = aid ? w3s : w1s;
        const float* Z = aid ? w3z : w1z;
        float s = S[(size_t)n * 64 + g], z = Z[(size_t)n * 64 + g];
        (aid ? g3 : g1)[r] = make_float2(s, z * s);
    } else {
        int n = r & (H_DIM - 1), g = r >> 12;
        float s = w2s[(size_t)n * 224 + g], z = w2z[(size_t)n * 224 + g];
        g2[r] = make_float2(s, z * s);
    }
}

// ---------------------------------------------------------------------------
// k_gemm1: barrier-free, LDS-free fused gate/up GEMM.
// Wave = 64M x 32N, K=4096 (128 steps of 32). 1792 waves = 896 blocks x 2.
// blk: m-slot = blk&3 (4 m-duplicates of a weight stripe adjacent -> L3 share),
//      nb = blk>>2; wave n0 = nb*64 + wid*32; m0 = m*64.
// Per step: 8 weight dwordx4 + 4 A dwordx4 (L2) + dequant(80 VALU-cyc)
//           + 16 MFMA (310 cyc). Depth-1 explicit weight prefetch; TLP does the rest.
// ---------------------------------------------------------------------------
template<bool TR>
__global__ __launch_bounds__(128, 2) void k_gemm1(
    const int* __restrict__ w1q, const int* __restrict__ w3q,
    const float* __restrict__ w1s, const float* __restrict__ w1z,
    const float* __restrict__ w3s, const float* __restrict__ w3z,
    const float2* __restrict__ g1, const float2* __restrict__ g3,
    const unsigned char* __restrict__ xs, unsigned short* __restrict__ act)
{
    const int tid = threadIdx.x, wid = tid >> 6, l = tid & 63;
    const int m  = blockIdx.x & 3, nb = blockIdx.x >> 2;
    const int n0 = nb * 64 + wid * 32;
    const int lr = l & 15, lk = l >> 4;
    const int rA = n0 + lr, rB = n0 + 16 + lr;     // weight rows this lane reads

    const int* p1A = w1q + (size_t)rA * H_DIM + lk * 8;
    const int* p1B = w1q + (size_t)rB * H_DIM + lk * 8;
    const int* p3A = w3q + (size_t)rA * H_DIM + lk * 8;
    const int* p3B = w3q + (size_t)rB * H_DIM + lk * 8;
    const unsigned char* xp = xs + (size_t)(m * 4) * 1024 + (size_t)l * 16;

    f4v ag[4][2], au[4][2];
    const f4v fz = {0.f, 0.f, 0.f, 0.f};
    #pragma unroll
    for (int i = 0; i < 4; ++i) { ag[i][0] = fz; ag[i][1] = fz; au[i][0] = fz; au[i][1] = fz; }

    auto ldsc = [&](int g, int row) -> float2 {
        if constexpr (TR) {
            return row < 16 ? g1[(size_t)g * I_DIM + (row == 0 ? rA : rB)]
                            : g3[(size_t)g * I_DIM + (row == 16 ? rA : rB)];
        } else {
            const float* S = row < 16 ? w1s : w3s;
            const float* Z = row < 16 ? w1z : w3z;
            int rr = (row & 15) == 0 ? rA : rB;
            float s = S[(size_t)rr * 64 + g], z = Z[(size_t)rr * 64 + g];
            return make_float2(s, z * s);
        }
    };
    // ldsc row codes: 0 = w1/rA, 1 = w1/rB, 16 = w3/rA, 17 = w3/rB

    // prologue: q(t=0), scales(g=0)
    int4 c1Aa = *(const int4*)p1A, c1Ab = *(const int4*)(p1A + 4);
    int4 c1Ba = *(const int4*)p1B, c1Bb = *(const int4*)(p1B + 4);
    int4 c3Aa = *(const int4*)p3A, c3Ab = *(const int4*)(p3A + 4);
    int4 c3Ba = *(const int4*)p3B, c3Bb = *(const int4*)(p3B + 4);
    float2 s1A = ldsc(0, 0), s1B = ldsc(0, 1), s3A = ldsc(0, 16), s3B = ldsc(0, 17);

    for (int g = 0; g < 64; ++g) {
        const int gn = g < 63 ? g + 1 : 63;
        float2 t1A = ldsc(gn, 0), t1B = ldsc(gn, 1), t3A = ldsc(gn, 16), t3B = ldsc(gn, 17);
        #pragma unroll
        for (int h = 0; h < 2; ++h) {
            const int t  = g * 2 + h;
            const int tn = t < 127 ? t + 1 : 127;
            // prefetch next-step weights (depth 1)
            int4 n1Aa = *(const int4*)(p1A + tn * 32), n1Ab = *(const int4*)(p1A + tn * 32 + 4);
            int4 n1Ba = *(const int4*)(p1B + tn * 32), n1Bb = *(const int4*)(p1B + tn * 32 + 4);
            int4 n3Aa = *(const int4*)(p3A + tn * 32), n3Ab = *(const int4*)(p3A + tn * 32 + 4);
            int4 n3Ba = *(const int4*)(p3B + tn * 32), n3Bb = *(const int4*)(p3B + tn * 32 + 4);
            // A-frags for this step (L2-resident xs)
            const unsigned char* xq = xp + (size_t)t * 16384;
            s8v a0 = *(const s8v*)(xq);
            s8v a1 = *(const s8v*)(xq + 1024);
            s8v a2 = *(const s8v*)(xq + 2048);
            s8v a3 = *(const s8v*)(xq + 3072);
            // dequant current step
            s8v b1A = dq8f(c1Aa, c1Ab, s1A.x, -s1A.y);
            s8v b1B = dq8f(c1Ba, c1Bb, s1B.x, -s1B.y);
            s8v b3A = dq8f(c3Aa, c3Ab, s3A.x, -s3A.y);
            s8v b3B = dq8f(c3Ba, c3Bb, s3B.x, -s3B.y);
            ag[0][0] = __builtin_amdgcn_mfma_f32_16x16x32_bf16(a0, b1A, ag[0][0], 0, 0, 0);
            ag[1][0] = __builtin_amdgcn_mfma_f32_16x16x32_bf16(a1, b1A, ag[1][0], 0, 0, 0);
            ag[2][0] = __builtin_amdgcn_mfma_f32_16x16x32_bf16(a2, b1A, ag[2][0], 0, 0, 0);
            ag[3][0] = __builtin_amdgcn_mfma_f32_16x16x32_bf16(a3, b1A, ag[3][0], 0, 0, 0);
            ag[0][1] = __builtin_amdgcn_mfma_f32_16x16x32_bf16(a0, b1B, ag[0][1], 0, 0, 0);
            ag[1][1] = __builtin_amdgcn_mfma_f32_16x16x32_bf16(a1, b1B, ag[1][1], 0, 0, 0);
            ag[2][1] = __builtin_amdgcn_mfma_f32_16x16x32_bf16(a2, b1B, ag[2][1], 0, 0, 0);
            ag[3][1] = __builtin_amdgcn_mfma_f32_16x16x32_bf16(a3, b1B, ag[3][1], 0, 0, 0);
            au[0][0] = __builtin_amdgcn_mfma_f32_16x16x32_bf16(a0, b3A, au[0][0], 0, 0, 0);
            au[1][0] = __builtin_amdgcn_mfma_f32_16x16x32_bf16(a1, b3A, au[1][0], 0, 0, 0);
            au[2][0] = __builtin_amdgcn_mfma_f32_16x16x32_bf16(a2, b3A, au[2][0], 0, 0, 0);
            au[3][0] = __builtin_amdgcn_mfma_f32_16x16x32_bf16(a3, b3A, au[3][0], 0, 0, 0);
            au[0][1] = __builtin_amdgcn_mfma_f32_16x16x32_bf16(a0, b3B, au[0][1], 0, 0, 0);
            au[1][1] = __builtin_amdgcn_mfma_f32_16x16x32_bf16(a1, b3B, au[1][1], 0, 0, 0);
            au[2][1] = __builtin_amdgcn_mfma_f32_16x16x32_bf16(a2, b3B, au[2][1], 0, 0, 0);
            au[3][1] = __builtin_amdgcn_mfma_f32_16x16x32_bf16(a3, b3B, au[3][1], 0, 0, 0);
            c1Aa = n1Aa; c1Ab = n1Ab; c1Ba = n1Ba; c1Bb = n1Bb;
            c3Aa = n3Aa; c3Ab = n3Ab; c3Ba = n3Ba; c3Bb = n3Bb;
        }
        s1A = t1A; s1B = t1B; s3A = t3A; s3B = t3B;
    }

    // epilogue: act = silu(g)*u, written A2-fragment-major for gemm2
    unsigned char* ab = (unsigned char*)act;
    #pragma unroll
    for (int mf = 0; mf < 4; ++mf) {
        const int msub = m * 4 + mf;
        #pragma unroll
        for (int nf = 0; nf < 2; ++nf)
            #pragma unroll
            for (int r = 0; r < 4; ++r) {
                const int N  = n0 + nf * 16 + lr;
                const int l2 = (lk * 4 + r) + (((N >> 3) & 3) << 4);
                float gg = ag[mf][nf][r], uu = au[mf][nf][r];
                float sg = gg / (1.0f + __expf(-gg));
                *(unsigned short*)(ab + ((size_t)((N >> 5) * 16 + msub) << 10)
                                      + l2 * 16 + (N & 7) * 2) = f2bf(sg * uu);
            }
    }
}

// ---------------------------------------------------------------------------
// k_gemm2: barrier-free, LDS-free. out = act @ w2^T, fp32 direct (no partials).
// Wave = 32M x 32N, K=14336 (448 steps). 1024 waves = 256 blocks x 4.
// blk&7 = m-slot (XCD-pinned: per-XCD 0.94MB act slice L2-resident),
// nb = blk>>3; wave n0 = nb*128 + wid*32; m0 = (blk&7)*32.
// Depth-2 weight prefetch (only 4 waves/CU here -> more ILP needed).
// ---------------------------------------------------------------------------
template<bool TR>
__global__ __launch_bounds__(256) void k_gemm2(
    const int* __restrict__ w2q,
    const float* __restrict__ w2s, const float* __restrict__ w2z,
    const float2* __restrict__ g2,
    const unsigned char* __restrict__ act, float* __restrict__ outp)
{
    const int tid = threadIdx.x, wid = tid >> 6, l = tid & 63;
    const int m  = blockIdx.x & 7, nb = blockIdx.x >> 3;
    const int n0 = nb * 128 + wid * 32;
    const int m0 = m * 32;
    const int lr = l & 15, lk = l >> 4;
    const int rA = n0 + lr, rB = n0 + 16 + lr;

    const int* pA = w2q + (size_t)rA * I_DIM + lk * 8;
    const int* pB = w2q + (size_t)rB * I_DIM + lk * 8;
    const unsigned char* xp = act + (size_t)(m * 2) * 1024 + (size_t)l * 16;

    f4v acc[2][2];
    const f4v fz = {0.f, 0.f, 0.f, 0.f};
    acc[0][0] = fz; acc[0][1] = fz; acc[1][0] = fz; acc[1][1] = fz;

    auto ldsc = [&](int g, int which) -> float2 {
        if constexpr (TR) {
            return g2[(size_t)g * H_DIM + (which ? rB : rA)];
        } else {
            int rr = which ? rB : rA;
            float s = w2s[(size_t)rr * 224 + g], z = w2z[(size_t)rr * 224 + g];
            return make_float2(s, z * s);
        }
    };

    // prologue: q(t=0) and q(t=1), scales g=0
    int4 cAa = *(const int4*)pA, cAb = *(const int4*)(pA + 4);
    int4 cBa = *(const int4*)pB, cBb = *(const int4*)(pB + 4);
    int4 dAa = *(const int4*)(pA + 32), dAb = *(const int4*)(pA + 36);
    int4 dBa = *(const int4*)(pB + 32), dBb = *(const int4*)(pB + 36);
    float2 sA = ldsc(0, 0), sB = ldsc(0, 1);

    for (int g = 0; g < 224; ++g) {
        const int gn = g < 223 ? g + 1 : 223;
        float2 tA = ldsc(gn, 0), tB = ldsc(gn, 1);
        #pragma unroll
        for (int h = 0; h < 2; ++h) {
            const int t  = g * 2 + h;
            const int tn = t < 446 ? t + 2 : 447;
            int4 nAa = *(const int4*)(pA + tn * 32), nAb = *(const int4*)(pA + tn * 32 + 4);
            int4 nBa = *(const int4*)(pB + tn * 32), nBb = *(const int4*)(pB + tn * 32 + 4);
            const unsigned char* xq = xp + (size_t)t * 16384;
            s8v a0 = *(const s8v*)(xq);
            s8v a1 = *(const s8v*)(xq + 1024);
            s8v bA = dq8f(cAa, cAb, sA.x, -sA.y);
            s8v bB = dq8f(cBa, cBb, sB.x, -sB.y);
            acc[0][0] = __builtin_amdgcn_mfma_f32_16x16x32_bf16(a0, bA, acc[0][0], 0, 0, 0);
            acc[1][0] = __builtin_amdgcn_mfma_f32_16x16x32_bf16(a1, bA, acc[1][0], 0, 0, 0);
            acc[0][1] = __builtin_amdgcn_mfma_f32_16x16x32_bf16(a0, bB, acc[0][1], 0, 0, 0);
            acc[1][1] = __builtin_amdgcn_mfma_f32_16x16x32_bf16(a1, bB, acc[1][1], 0, 0, 0);
            cAa = dAa; cAb = dAb; cBa = dBa; cBb = dBb;
            dAa = nAa; dAb = nAb; dBa = nBa; dBb = nBb;
        }
        sA = tA; sB = tB;
    }

    #pragma unroll
    for (int mf = 0; mf < 2; ++mf)
        #pragma unroll
        for (int nf = 0; nf < 2; ++nf)
            #pragma unroll
            for (int r = 0; r < 4; ++r) {
                const int M = m0 + mf * 16 + lk * 4 + r;
                const int N = n0 + nf * 16 + lr;
                outp[(size_t)M * H_DIM + N] = acc[mf][nf][r];
            }
}

extern "C" void kernel_launch(void* const* d_in, const int* in_sizes, int n_in,
                              void* d_out, int out_size, void* d_ws, size_t ws_size,
                              hipStream_t stream) {
    const float* x   = (const float*)d_in[0];
    const int*   w1q = (const int*)  d_in[1];
    const float* w1s = (const float*)d_in[2];
    const float* w1z = (const float*)d_in[3];
    const int*   w3q = (const int*)  d_in[4];
    const float* w3s = (const float*)d_in[5];
    const float* w3z = (const float*)d_in[6];
    const int*   w2q = (const int*)  d_in[7];
    const float* w2s = (const float*)d_in[8];
    const float* w2z = (const float*)d_in[9];
    float* outp = (float*)d_out;

    unsigned short* xs  = (unsigned short*)((char*)d_ws + XS_OFF);
    unsigned short* act = (unsigned short*)((char*)d_ws + ACT_OFF);
    float2* g1 = (float2*)((char*)d_ws + G1_OFF);
    float2* g3 = (float2*)((char*)d_ws + G3_OFF);
    float2* g2 = (float2*)((char*)d_ws + G2_OFF);
    const bool tr = (ws_size >= WS_NEED);

    k_prep<<<512, 256, 0, stream>>>(x, xs);
    if (tr) {
        t_prep<<<10752, 256, 0, stream>>>(w1s, w1z, w3s, w3z, w2s, w2z, g1, g3, g2);
        k_gemm1<true><<<896, 128, 0, stream>>>(w1q, w3q, w1s, w1z, w3s, w3z, g1, g3,
                                               (const unsigned char*)xs, act);
        k_gemm2<true><<<256, 256, 0, stream>>>(w2q, w2s, w2z, g2,
                                               (const unsigned char*)act, outp);
    } else {
        k_gemm1<false><<<896, 128, 0, stream>>>(w1q, w3q, w1s, w1z, w3s, w3z, g1, g3,
                                                (const unsigned char*)xs, act);
        k_gemm2<false><<<256, 256, 0, stream>>>(w2q, w2s, w2z, g2,
                                                (const unsigned char*)act, outp);
    }
}

// Round 7
// 411.566 us; speedup vs baseline: 2.1421x; 2.1421x over previous
//
#include <hip/hip_runtime.h>
#include <cstdint>
#include <cstddef>

#define T_DIM 256
#define H_DIM 4096
#define I_DIM 14336
// GROUP_SIZE = 64 == BK: one (scale,zero) per row per K-tile.

typedef __attribute__((ext_vector_type(8))) short s8v;   // 8 bf16 (A/B frag regs)
typedef __attribute__((ext_vector_type(4))) short s4v;   // 4 bf16
typedef __attribute__((ext_vector_type(4))) float f4v;   // MFMA C/D frag

// Workspace layout
static constexpr size_t XS_OFF    = 0;                                  // x bf16 frag-major, 2 MiB
static constexpr size_t ACT_OFF   = (size_t)T_DIM * H_DIM * 2;
static constexpr size_t ACT_BYTES = (size_t)T_DIM * I_DIM * 2;          // 7.34 MB
static constexpr size_t PRT_OFF   = ACT_OFF + ACT_BYTES;
static constexpr size_t PRT_BYTES = 4ull * T_DIM * H_DIM * 4;           // 16 MiB
static constexpr size_t WS_NEED   = PRT_OFF + PRT_BYTES;

__device__ __forceinline__ unsigned short f2bf(float f) {
    unsigned u = __builtin_bit_cast(unsigned, f);
    u += 0x7fffu + ((u >> 16) & 1u);
    return (unsigned short)(u >> 16);
}

__device__ __forceinline__ void g2lds16(const void* g, void* l) {
    // global->LDS DMA, 16B/lane; lds ptr is wave-uniform base (HW adds lane*16)
    __builtin_amdgcn_global_load_lds(
        (const __attribute__((address_space(1))) unsigned int*)g,
        (__attribute__((address_space(3))) unsigned int*)l,
        16, 0, 0);
}

__device__ __forceinline__ s4v dq4(const int4 q, float s, float ns) {
    union { unsigned short u[4]; s4v v; } r;
    r.u[0] = f2bf(fmaf((float)q.x, s, ns));
    r.u[1] = f2bf(fmaf((float)q.y, s, ns));
    r.u[2] = f2bf(fmaf((float)q.z, s, ns));
    r.u[3] = f2bf(fmaf((float)q.w, s, ns));
    return r.v;
}

// ---------------------------------------------------------------------------
// k_prep: x fp32 [256,4096] -> bf16 A-fragment-major for BM=128 tiles:
// idx16 = (kt*2 + mhalf)*16 + ksub*8 + msub ; lane = (m&15) + 16*((k>>3)&3);
// byte = idx16*1024 + lane*16 + (k&7)*2.
// ---------------------------------------------------------------------------
__global__ __launch_bounds__(256) void k_prep(const float* __restrict__ x,
                                              unsigned short* __restrict__ xs) {
    int t = blockIdx.x * 256 + threadIdx.x;    // 131072 threads, 8 bf16 each
    int m = t >> 9, slot = t & 511;
    int k0 = slot * 8;
    const float* xp = x + (size_t)m * H_DIM + k0;
    float4 a = *(const float4*)xp;
    float4 b = *(const float4*)(xp + 4);
    union { unsigned short u[8]; s8v v; } r;
    r.u[0] = f2bf(a.x); r.u[1] = f2bf(a.y); r.u[2] = f2bf(a.z); r.u[3] = f2bf(a.w);
    r.u[4] = f2bf(b.x); r.u[5] = f2bf(b.y); r.u[6] = f2bf(b.z); r.u[7] = f2bf(b.w);
    int idx16 = ((k0 >> 6) * 2 + (m >> 7)) * 16 + ((k0 >> 5) & 1) * 8 + ((m >> 4) & 7);
    int lane  = (m & 15) + 16 * ((k0 >> 3) & 3);
    *(s8v*)((unsigned char*)xs + (size_t)idx16 * 1024 + lane * 16) = r.v;
}

// ---------------------------------------------------------------------------
// k_gemm1: fused gate/up GEMM. BM=128, BN=32, BK=64, grid 896 = 56x(2 mh)x8.
// 4 waves; x staged via linear g2lds into frag-major LDS; weights reg-staged,
// dequanted into frag-major LDS. 48 KB LDS -> 3 blocks/CU. Plain barriers;
// cross-block overlap hides the per-tile drain. mh-pairs share an XCD (L2).
// ---------------------------------------------------------------------------
struct W1R { int4 q1a, q1b, q3a, q3b;
             float s1a, z1a, s1b, z1b, s3a, z3a, s3b, z3b; };

__global__ __launch_bounds__(256, 3) void k_gemm1(
    const int* __restrict__ w1q, const float* __restrict__ w1s, const float* __restrict__ w1z,
    const int* __restrict__ w3q, const float* __restrict__ w3s, const float* __restrict__ w3z,
    const unsigned char* __restrict__ xs, unsigned char* __restrict__ act)
{
    __shared__ unsigned char xbuf[2][16384];
    __shared__ unsigned char wbuf[2][8192];     // per buf: w1 4K @0, w3 4K @4096
    const int tid = threadIdx.x;
    const int bx  = blockIdx.x;
    const int nb  = (bx >> 4) * 8 + (bx & 7);   // 0..447 ; bx%8 = XCD slot
    const int mh  = (bx >> 3) & 1;              // mh-pair shares bx%8 -> same XCD
    const int n0  = nb * 32;
    const int wid = tid >> 6, l = tid & 63;
    const int lr  = l & 15, lk = l >> 4;

    // weight staging map: row = tid>>4 (0..15; +16 via *hi), h = tid&15
    const int row = tid >> 4, h = tid & 15;
    const int4* w1lo = (const int4*)w1q + (size_t)(n0 + row) * 1024;
    const int4* w1hi = w1lo + (size_t)16 * 1024;
    const int4* w3lo = (const int4*)w3q + (size_t)(n0 + row) * 1024;
    const int4* w3hi = w3lo + (size_t)16 * 1024;
    const float* s1lo = w1s + (size_t)(n0 + row) * 64; const float* s1hi = s1lo + 16 * 64;
    const float* z1lo = w1z + (size_t)(n0 + row) * 64; const float* z1hi = z1lo + 16 * 64;
    const float* s3lo = w3s + (size_t)(n0 + row) * 64; const float* s3hi = s3lo + 16 * 64;
    const float* z3lo = w3z + (size_t)(n0 + row) * 64; const float* z3hi = z3lo + 16 * 64;
    // frag-major write offsets (k = 4h..4h+3 of this tile)
    const int wlane = row + 16 * ((h & 7) >> 1);
    const int ks_s  = h >> 3;
    const int wb0 = (ks_s * 2 + 0) * 1024 + wlane * 16 + (h & 1) * 8;   // rows n0+0..15
    const int wb1 = (ks_s * 2 + 1) * 1024 + wlane * 16 + (h & 1) * 8;   // rows n0+16..31

    f4v ag[2][2], au[2][2];
    const f4v fz = {0.f, 0.f, 0.f, 0.f};
    #pragma unroll
    for (int i = 0; i < 2; ++i)
        #pragma unroll
        for (int j = 0; j < 2; ++j) { ag[i][j] = fz; au[i][j] = fz; }

    auto wload = [&](int kt, W1R& w) {
        w.q1a = w1lo[kt * 16 + h]; w.q1b = w1hi[kt * 16 + h];
        w.q3a = w3lo[kt * 16 + h]; w.q3b = w3hi[kt * 16 + h];
        w.s1a = s1lo[kt]; w.z1a = z1lo[kt]; w.s1b = s1hi[kt]; w.z1b = z1hi[kt];
        w.s3a = s3lo[kt]; w.z3a = z3lo[kt]; w.s3b = s3hi[kt]; w.z3b = z3hi[kt];
    };
    auto wstore = [&](const W1R& w, unsigned char* b) {
        *(s4v*)(b + wb0)        = dq4(w.q1a, w.s1a, -w.z1a * w.s1a);
        *(s4v*)(b + wb1)        = dq4(w.q1b, w.s1b, -w.z1b * w.s1b);
        *(s4v*)(b + 4096 + wb0) = dq4(w.q3a, w.s3a, -w.z3a * w.s3a);
        *(s4v*)(b + 4096 + wb1) = dq4(w.q3b, w.s3b, -w.z3b * w.s3b);
    };
    auto xstage = [&](int kt, unsigned char* dst) {
        const unsigned char* src = xs + (size_t)(kt * 2 + mh) * 16384
                                      + wid * 4096 + (size_t)l * 16;
        unsigned char* d = dst + wid * 4096;    // wave-uniform
        #pragma unroll
        for (int j = 0; j < 4; ++j)
            g2lds16(src + j * 1024, d + j * 1024);
    };
    auto compute = [&](const unsigned char* xb, const unsigned char* wb) {
        #pragma unroll
        for (int ks = 0; ks < 2; ++ks) {
            s8v a0  = *(const s8v*)(xb + (ks * 8 + wid * 2 + 0) * 1024 + l * 16);
            s8v a1  = *(const s8v*)(xb + (ks * 8 + wid * 2 + 1) * 1024 + l * 16);
            s8v b1a = *(const s8v*)(wb + (ks * 2 + 0) * 1024 + l * 16);
            s8v b1b = *(const s8v*)(wb + (ks * 2 + 1) * 1024 + l * 16);
            s8v b3a = *(const s8v*)(wb + 4096 + (ks * 2 + 0) * 1024 + l * 16);
            s8v b3b = *(const s8v*)(wb + 4096 + (ks * 2 + 1) * 1024 + l * 16);
            ag[0][0] = __builtin_amdgcn_mfma_f32_16x16x32_bf16(a0, b1a, ag[0][0], 0, 0, 0);
            ag[1][0] = __builtin_amdgcn_mfma_f32_16x16x32_bf16(a1, b1a, ag[1][0], 0, 0, 0);
            ag[0][1] = __builtin_amdgcn_mfma_f32_16x16x32_bf16(a0, b1b, ag[0][1], 0, 0, 0);
            ag[1][1] = __builtin_amdgcn_mfma_f32_16x16x32_bf16(a1, b1b, ag[1][1], 0, 0, 0);
            au[0][0] = __builtin_amdgcn_mfma_f32_16x16x32_bf16(a0, b3a, au[0][0], 0, 0, 0);
            au[1][0] = __builtin_amdgcn_mfma_f32_16x16x32_bf16(a1, b3a, au[1][0], 0, 0, 0);
            au[0][1] = __builtin_amdgcn_mfma_f32_16x16x32_bf16(a0, b3b, au[0][1], 0, 0, 0);
            au[1][1] = __builtin_amdgcn_mfma_f32_16x16x32_bf16(a1, b3b, au[1][1], 0, 0, 0);
        }
    };

    W1R W;
    wload(0, W);
    xstage(0, xbuf[0]);
    wstore(W, wbuf[0]);          // compiler-counted wait on W's loads
    __syncthreads();             // drains g2lds(0) + makes w(0) visible

    for (int t = 0; t < 64; ++t) {
        const int cur = t & 1;
        if (t < 63) {
            wload(t + 1, W);             // prefetch weights for t+1
            xstage(t + 1, xbuf[cur ^ 1]);// prefetch x for t+1 (other buffer)
        }
        __builtin_amdgcn_sched_barrier(0);
        compute(xbuf[cur], wbuf[cur]);   // pure ds_read + MFMA
        __syncthreads();                 // drain: t+1 loads landed, reads done
        if (t < 63) wstore(W, wbuf[cur ^ 1]);
        __syncthreads();                 // dequanted tile visible
    }

    // epilogue: act = silu(g)*u, written A-frag-major for gemm2 (BM=256 tiles)
    #pragma unroll
    for (int mf = 0; mf < 2; ++mf)
        #pragma unroll
        for (int nf = 0; nf < 2; ++nf)
            #pragma unroll
            for (int r = 0; r < 4; ++r) {
                float g = ag[mf][nf][r], u = au[mf][nf][r];
                float sg = g / (1.0f + __expf(-g));
                const int idx16 = (nb >> 1) * 32 + (nb & 1) * 16 + mh * 8 + wid * 2 + mf;
                const int lane2 = (lk * 4 + r) + 16 * (nf * 2 + (lr >> 3));
                *(unsigned short*)(act + (size_t)idx16 * 1024 + lane2 * 16
                                       + (lr & 7) * 2) = f2bf(sg * u);
            }
}

// ---------------------------------------------------------------------------
// k_gemm2: out_partial[kc] = act[:, kc-chunk] @ w2[:, kc-chunk]^T.
// BM=256, BN=32, 4 K-chunks x 56 tiles; grid 512; kc pinned to XCD-pairs so
// each 1.83 MB act slice is L2-resident. 8 waves, 72 KB LDS -> 2 blocks/CU.
// ---------------------------------------------------------------------------
struct W2R { int4 q2; float s2, z2; };

template<bool ATOMIC>
__global__ __launch_bounds__(512, 4) void k_gemm2(
    const int* __restrict__ w2q, const float* __restrict__ w2s, const float* __restrict__ w2z,
    const unsigned char* __restrict__ act, float* __restrict__ outp)
{
    __shared__ unsigned char xbuf[2][32768];
    __shared__ unsigned char wbuf[2][4096];
    const int tid = threadIdx.x;
    const int bx  = blockIdx.x;
    const int kc  = (bx & 7) >> 1;               // K-chunk per XCD-pair
    const int nb  = (bx >> 3) * 2 + (bx & 1);    // 0..127
    const int n0  = nb * 32;
    const int wid = tid >> 6, l = tid & 63;
    const int lr  = l & 15, lk = l >> 4;

    const int row = tid >> 4, h = tid & 15;      // row 0..31
    const int4* w2p = (const int4*)w2q + (size_t)(n0 + row) * 3584 + (size_t)kc * 896;
    const float* s2p = w2s + (size_t)(n0 + row) * 224 + kc * 56;
    const float* z2p = w2z + (size_t)(n0 + row) * 224 + kc * 56;
    const int wlane = (row & 15) + 16 * ((h & 7) >> 1);
    const int wb    = ((h >> 3) * 2 + (row >> 4)) * 1024 + wlane * 16 + (h & 1) * 8;

    f4v acc[2][2];
    const f4v fz = {0.f, 0.f, 0.f, 0.f};
    acc[0][0] = fz; acc[0][1] = fz; acc[1][0] = fz; acc[1][1] = fz;

    auto wload = [&](int kt, W2R& w) {
        w.q2 = w2p[kt * 16 + h];
        w.s2 = s2p[kt]; w.z2 = z2p[kt];
    };
    auto wstore = [&](const W2R& w, unsigned char* b) {
        *(s4v*)(b + wb) = dq4(w.q2, w.s2, -w.z2 * w.s2);
    };
    auto xstage = [&](int kt, unsigned char* dst) {
        const unsigned char* src = act + (size_t)(kc * 56 + kt) * 32768
                                       + wid * 4096 + (size_t)l * 16;
        unsigned char* d = dst + wid * 4096;
        #pragma unroll
        for (int j = 0; j < 4; ++j)
            g2lds16(src + j * 1024, d + j * 1024);
    };
    auto compute = [&](const unsigned char* xb, const unsigned char* wbp) {
        #pragma unroll
        for (int ks = 0; ks < 2; ++ks) {
            s8v a0 = *(const s8v*)(xb + (ks * 16 + wid * 2 + 0) * 1024 + l * 16);
            s8v a1 = *(const s8v*)(xb + (ks * 16 + wid * 2 + 1) * 1024 + l * 16);
            s8v b0 = *(const s8v*)(wbp + (ks * 2 + 0) * 1024 + l * 16);
            s8v b1 = *(const s8v*)(wbp + (ks * 2 + 1) * 1024 + l * 16);
            acc[0][0] = __builtin_amdgcn_mfma_f32_16x16x32_bf16(a0, b0, acc[0][0], 0, 0, 0);
            acc[1][0] = __builtin_amdgcn_mfma_f32_16x16x32_bf16(a1, b0, acc[1][0], 0, 0, 0);
            acc[0][1] = __builtin_amdgcn_mfma_f32_16x16x32_bf16(a0, b1, acc[0][1], 0, 0, 0);
            acc[1][1] = __builtin_amdgcn_mfma_f32_16x16x32_bf16(a1, b1, acc[1][1], 0, 0, 0);
        }
    };

    W2R W;
    wload(0, W);
    xstage(0, xbuf[0]);
    wstore(W, wbuf[0]);
    __syncthreads();

    for (int t = 0; t < 56; ++t) {
        const int cur = t & 1;
        if (t < 55) {
            wload(t + 1, W);
            xstage(t + 1, xbuf[cur ^ 1]);
        }
        __builtin_amdgcn_sched_barrier(0);
        compute(xbuf[cur], wbuf[cur]);
        __syncthreads();
        if (t < 55) wstore(W, wbuf[cur ^ 1]);
        __syncthreads();
    }

    float* pout = outp + (ATOMIC ? 0 : (size_t)kc * ((size_t)T_DIM * H_DIM));
    #pragma unroll
    for (int mf = 0; mf < 2; ++mf)
        #pragma unroll
        for (int nf = 0; nf < 2; ++nf)
            #pragma unroll
            for (int r = 0; r < 4; ++r) {
                const int M = wid * 32 + mf * 16 + lk * 4 + r;
                const int N = n0 + nf * 16 + lr;
                if (ATOMIC) atomicAdd(&outp[(size_t)M * H_DIM + N], acc[mf][nf][r]);
                else        pout[(size_t)M * H_DIM + N] = acc[mf][nf][r];
            }
}

__global__ __launch_bounds__(256) void k_reduce(const f4v* __restrict__ p,
                                                f4v* __restrict__ o) {
    int i = blockIdx.x * 256 + threadIdx.x;   // 262144 f4 groups
    f4v s = p[i];
    #pragma unroll
    for (int c = 1; c < 4; ++c) s += p[(size_t)c * 262144 + i];
    o[i] = s;
}

__global__ __launch_bounds__(256) void k_zero(f4v* __restrict__ o) {
    o[blockIdx.x * 256 + threadIdx.x] = (f4v){0.f, 0.f, 0.f, 0.f};
}

extern "C" void kernel_launch(void* const* d_in, const int* in_sizes, int n_in,
                              void* d_out, int out_size, void* d_ws, size_t ws_size,
                              hipStream_t stream) {
    const float* x   = (const float*)d_in[0];
    const int*   w1q = (const int*)  d_in[1];
    const float* w1s = (const float*)d_in[2];
    const float* w1z = (const float*)d_in[3];
    const int*   w3q = (const int*)  d_in[4];
    const float* w3s = (const float*)d_in[5];
    const float* w3z = (const float*)d_in[6];
    const int*   w2q = (const int*)  d_in[7];
    const float* w2s = (const float*)d_in[8];
    const float* w2z = (const float*)d_in[9];
    float* outp = (float*)d_out;

    unsigned short* xs  = (unsigned short*)((char*)d_ws + XS_OFF);
    unsigned char*  act = (unsigned char*)d_ws + ACT_OFF;
    float*          prt = (float*)((char*)d_ws + PRT_OFF);
    const bool partials = (ws_size >= WS_NEED);

    k_prep<<<512, 256, 0, stream>>>(x, xs);
    k_gemm1<<<896, 256, 0, stream>>>(w1q, w1s, w1z, w3q, w3s, w3z,
                                     (const unsigned char*)xs, act);
    if (partials) {
        k_gemm2<false><<<512, 512, 0, stream>>>(w2q, w2s, w2z, act, prt);
        k_reduce<<<1024, 256, 0, stream>>>((const f4v*)prt, (f4v*)outp);
    } else {
        k_zero<<<1024, 256, 0, stream>>>((f4v*)outp);
        k_gemm2<true><<<512, 512, 0, stream>>>(w2q, w2s, w2z, act, outp);
    }
}